// Round 6
// baseline (310.334 us; speedup 1.0000x reference)
//
#include <hip/hip_runtime.h>
#include <hip/hip_bf16.h>
#include <stdint.h>

#define NN 50000
#define NE 625000
#define DD 128
#define NL 3
#define GB 391  // gemm blocks = ceil(NN/128)

typedef __bf16 bf16x8 __attribute__((ext_vector_type(8)));
typedef float f32x4 __attribute__((ext_vector_type(4)));

__device__ __forceinline__ float bflo(uint32_t u) { return __uint_as_float(u << 16); }
__device__ __forceinline__ float bfhi(uint32_t u) { return __uint_as_float(u & 0xffff0000u); }
__device__ __forceinline__ float bf1(uint16_t u) { return __uint_as_float(((uint32_t)u) << 16); }
__device__ __forceinline__ uint16_t f2bf(float f) {
    __hip_bfloat16 h = __float2bfloat16(f);
    return __builtin_bit_cast(uint16_t, h);
}
__device__ __forceinline__ uint32_t pack2(float lo, float hi) {
    return (uint32_t)f2bf(lo) | ((uint32_t)f2bf(hi) << 16);
}

// ---------------- CSR construction ----------------
__global__ void k_hist(const int* __restrict__ dstv, int* __restrict__ deg) {
    int e = blockIdx.x * 256 + threadIdx.x;
    if (e < NE) atomicAdd(&deg[dstv[e]], 1);
}

__global__ __launch_bounds__(512) void k_bsum(const int* __restrict__ deg, int* __restrict__ bsum) {
    __shared__ int s[512];
    int i = blockIdx.x * 512 + threadIdx.x;
    int v = (i < NN) ? deg[i] : 0;
    s[threadIdx.x] = v;
    __syncthreads();
    for (int st = 256; st > 0; st >>= 1) {
        if (threadIdx.x < st) s[threadIdx.x] += s[threadIdx.x + st];
        __syncthreads();
    }
    if (threadIdx.x == 0) bsum[blockIdx.x] = s[0];
}

__global__ __launch_bounds__(128) void k_scanbs(const int* __restrict__ bsum, int* __restrict__ bsoff) {
    __shared__ int s[128];
    int t = threadIdx.x;
    int v = (t < 98) ? bsum[t] : 0;
    s[t] = v;
    __syncthreads();
    for (int st = 1; st < 128; st <<= 1) {
        int a = (t >= st) ? s[t - st] : 0;
        __syncthreads();
        s[t] += a;
        __syncthreads();
    }
    if (t < 98) bsoff[t] = s[t] - v;
}

__global__ __launch_bounds__(512) void k_scan2(int* __restrict__ deg_cursor,
                                               const int* __restrict__ bsoff,
                                               int* __restrict__ rowptr) {
    __shared__ int s[512];
    int t = threadIdx.x;
    int i = blockIdx.x * 512 + t;
    int v = (i < NN) ? deg_cursor[i] : 0;
    s[t] = v;
    __syncthreads();
    for (int st = 1; st < 512; st <<= 1) {
        int a = (t >= st) ? s[t - st] : 0;
        __syncthreads();
        s[t] += a;
        __syncthreads();
    }
    if (i < NN) {
        int excl = bsoff[blockIdx.x] + s[t] - v;
        rowptr[i] = excl;
        deg_cursor[i] = excl;  // becomes fill cursor
        if (i == NN - 1) rowptr[NN] = excl + v;
    }
}

__global__ void k_fill(const int* __restrict__ srcv, const int* __restrict__ dstv,
                       int* __restrict__ cursor, int* __restrict__ colv) {
    int e = blockIdx.x * 256 + threadIdx.x;
    if (e < NE) {
        int d = dstv[e];
        int p = atomicAdd(&cursor[d], 1);
        colv[p] = srcv[e];
    }
}

// ---------------- weight convert (f32 [k][col] -> bf16 transposed+swizzled image) ----------------
__global__ void k_convert_w(const float* __restrict__ W1, const float* __restrict__ W2,
                            const float* __restrict__ Wl, uint16_t* __restrict__ Wb) {
    int id = blockIdx.x * 256 + threadIdx.x;
    if (id >= 9 * 16384) return;
    int m = id >> 14;
    int r = id & 16383;
    int k = r >> 7;
    int col = r & 127;
    const float* src;
    if (m < 3) src = W1 + m * 16384;
    else if (m < 6) src = W2 + (m - 3) * 16384;
    else src = Wl + (m - 6) * 16384;
    float v = src[k * 128 + col];
    // image layout: [col][k] with k-index XOR-swizzled by (col&7)<<3 (units of bf16 elements)
    Wb[m * 16384 + col * 128 + (k ^ ((col & 7) << 3))] = f2bf(v);
}

// also zeroes the CSR cursor and the layer-barrier counter
__global__ void k_x2bf(const float* __restrict__ x, uint16_t* __restrict__ hb,
                       int* __restrict__ cursor, int* __restrict__ barcnt) {
    int id = blockIdx.x * 256 + threadIdx.x;
    if (id == 0) *barcnt = 0;
    if (id < NN) cursor[id] = 0;
    int base = id * 4;
    if (base >= NN * DD) return;
    float4 v = *(const float4*)(x + base);
    uint2 st;
    st.x = pack2(v.x, v.y);
    st.y = pack2(v.z, v.w);
    *(uint2*)(hb + base) = st;
}

// ---------------- aggregation: z = (1+eps)*h + sum_{src in N(dst)} h[src] ----------------
// 16 lanes per node, 4 nodes per wave, edge loop unrolled x4.
// Block 0 also zeroes bnsum for this layer's stats (stream-order safe).
__global__ __launch_bounds__(256) void k_agg(const uint16_t* __restrict__ hb,
                                             const int* __restrict__ rowptr,
                                             const int* __restrict__ colv,
                                             const float* __restrict__ epsp, int layer,
                                             uint16_t* __restrict__ zb,
                                             float* __restrict__ bnsum) {
    if (blockIdx.x == 0) bnsum[threadIdx.x] = 0.f;  // 256 threads cover 256 floats
    int g = (blockIdx.x * 256 + threadIdx.x) >> 4;  // node id
    int l16 = threadIdx.x & 15;
    if (g >= NN) return;
    float onepe = 1.0f + epsp[layer];
    int beg = rowptr[g], end = rowptr[g + 1];
    const uint4* hp = (const uint4*)hb;  // row = 16 uint4
    float a0 = 0.f, a1 = 0.f, a2 = 0.f, a3 = 0.f, a4 = 0.f, a5 = 0.f, a6 = 0.f, a7 = 0.f;
    int j = beg;
    for (; j + 3 < end; j += 4) {
        int s0 = colv[j];
        int s1 = colv[j + 1];
        int s2 = colv[j + 2];
        int s3 = colv[j + 3];
        uint4 u0 = hp[(size_t)s0 * 16 + l16];
        uint4 u1 = hp[(size_t)s1 * 16 + l16];
        uint4 u2 = hp[(size_t)s2 * 16 + l16];
        uint4 u3 = hp[(size_t)s3 * 16 + l16];
        a0 += bflo(u0.x); a1 += bfhi(u0.x); a2 += bflo(u0.y); a3 += bfhi(u0.y);
        a4 += bflo(u0.z); a5 += bfhi(u0.z); a6 += bflo(u0.w); a7 += bfhi(u0.w);
        a0 += bflo(u1.x); a1 += bfhi(u1.x); a2 += bflo(u1.y); a3 += bfhi(u1.y);
        a4 += bflo(u1.z); a5 += bfhi(u1.z); a6 += bflo(u1.w); a7 += bfhi(u1.w);
        a0 += bflo(u2.x); a1 += bfhi(u2.x); a2 += bflo(u2.y); a3 += bfhi(u2.y);
        a4 += bflo(u2.z); a5 += bfhi(u2.z); a6 += bflo(u2.w); a7 += bfhi(u2.w);
        a0 += bflo(u3.x); a1 += bfhi(u3.x); a2 += bflo(u3.y); a3 += bfhi(u3.y);
        a4 += bflo(u3.z); a5 += bfhi(u3.z); a6 += bflo(u3.w); a7 += bfhi(u3.w);
    }
    for (; j < end; ++j) {
        int s0 = colv[j];
        uint4 u = hp[(size_t)s0 * 16 + l16];
        a0 += bflo(u.x); a1 += bfhi(u.x); a2 += bflo(u.y); a3 += bfhi(u.y);
        a4 += bflo(u.z); a5 += bfhi(u.z); a6 += bflo(u.w); a7 += bfhi(u.w);
    }
    uint4 hu = hp[(size_t)g * 16 + l16];
    a0 = fmaf(onepe, bflo(hu.x), a0); a1 = fmaf(onepe, bfhi(hu.x), a1);
    a2 = fmaf(onepe, bflo(hu.y), a2); a3 = fmaf(onepe, bfhi(hu.y), a3);
    a4 = fmaf(onepe, bflo(hu.z), a4); a5 = fmaf(onepe, bfhi(hu.z), a5);
    a6 = fmaf(onepe, bflo(hu.w), a6); a7 = fmaf(onepe, bfhi(hu.w), a7);
    uint4 st;
    st.x = pack2(a0, a1); st.y = pack2(a2, a3);
    st.z = pack2(a4, a5); st.w = pack2(a6, a7);
    ((uint4*)zb)[(size_t)g * 16 + l16] = st;
}

// ---------------- fused layer: MLP + BN(grid barrier) + skip + relu + hnext + out GEMM ----------------
// LDS = 65KB -> exactly 2 blocks/CU -> 512 slots >= 391 blocks all co-resident, so the
// device-scope spin barrier cannot deadlock. __launch_bounds__(256,2) caps VGPR<=256 so
// occupancy stays 2 blocks/CU. Barrier counter is monotonic within one kernel_launch
// (target = (layer+1)*GB), zeroed each call by k_x2bf.
__global__ __launch_bounds__(256, 2) void k_layer(
    const uint16_t* __restrict__ zb, const uint16_t* __restrict__ hprev,
    const uint16_t* __restrict__ W1img, const uint16_t* __restrict__ W2img,
    const uint16_t* __restrict__ Wlimg,
    const float* __restrict__ b1, const float* __restrict__ b2,
    const float* __restrict__ blv,
    const float* __restrict__ gammal, const float* __restrict__ betal,
    int has_skip, float* __restrict__ bnsum, int* __restrict__ barcnt, int target,
    uint16_t* __restrict__ hnext, float* __restrict__ outl) {
    __shared__ uint16_t ldsW[16384];  // 32KB: W1 -> W2 -> hprev image -> Wl
    __shared__ uint16_t ldsT[16384];  // 32KB: t1 image -> stats scratch -> hnext image
    __shared__ float sAB[256];

    int tid = threadIdx.x;
    int wid = tid >> 6, lane = tid & 63;
    const int brow = blockIdx.x * 128;
    const int m0 = wid * 32;
    const int l15 = lane & 15;
    const int lhi = lane >> 4;

    // prefetch W2 image into registers
    bf16x8 wpre[8];
#pragma unroll
    for (int it = 0; it < 8; ++it) wpre[it] = *(const bf16x8*)(W2img + (it * 256 + tid) * 8);
    // stage W1 image
#pragma unroll
    for (int it = 0; it < 8; ++it) {
        int idx = (it * 256 + tid) * 8;
        *(bf16x8*)(&ldsW[idx]) = *(const bf16x8*)(W1img + idx);
    }
    __syncthreads();

    f32x4 acc[2][8];
    f32x4 zero = {0.f, 0.f, 0.f, 0.f};
#pragma unroll
    for (int m = 0; m < 2; ++m)
#pragma unroll
        for (int n = 0; n < 8; ++n) acc[m][n] = zero;

    // ---- GEMM1: A = zb (global) ----
    const char* Ab = (const char*)zb;
#pragma unroll
    for (int kk = 0; kk < 4; ++kk) {
        int kbyte = kk * 64 + (lhi << 4);
        bf16x8 afrag[2];
#pragma unroll
        for (int m = 0; m < 2; ++m) {
            int row = brow + m0 + m * 16 + l15;
            if (row >= NN) row = NN - 1;
            afrag[m] = *(const bf16x8*)(Ab + (size_t)row * 256 + kbyte);
        }
#pragma unroll
        for (int n = 0; n < 8; ++n) {
            int col = n * 16 + l15;
            int addr = col * 256 + (kbyte ^ ((col & 7) << 4));
            bf16x8 bfrag = *(const bf16x8*)((const char*)ldsW + addr);
            acc[0][n] = __builtin_amdgcn_mfma_f32_16x16x32_bf16(afrag[0], bfrag, acc[0][n], 0, 0, 0);
            acc[1][n] = __builtin_amdgcn_mfma_f32_16x16x32_bf16(afrag[1], bfrag, acc[1][n], 0, 0, 0);
        }
    }

    // ---- epilogue1: relu(acc + b1) -> ldsT (bf16, image layout) ----
    {
        float bc[8];
#pragma unroll
        for (int n = 0; n < 8; ++n) bc[n] = b1[n * 16 + l15];
#pragma unroll
        for (int m = 0; m < 2; ++m) {
            int rbase = m0 + m * 16 + (lhi << 2);
#pragma unroll
            for (int r = 0; r < 4; ++r) {
                int row = rbase + r;
#pragma unroll
                for (int n = 0; n < 8; ++n) {
                    float v = fmaxf(acc[m][n][r] + bc[n], 0.f);
                    int col = n * 16 + l15;
                    int byteoff = row * 256 + ((col * 2) ^ ((row & 7) << 4));
                    *(uint16_t*)((char*)ldsT + byteoff) = f2bf(v);
                }
            }
        }
    }
    __syncthreads();

    // stage W2 from regs; prefetch Wl into regs (loads fly during GEMM2)
#pragma unroll
    for (int it = 0; it < 8; ++it) *(bf16x8*)(&ldsW[(it * 256 + tid) * 8]) = wpre[it];
#pragma unroll
    for (int it = 0; it < 8; ++it) wpre[it] = *(const bf16x8*)(Wlimg + (it * 256 + tid) * 8);
    __syncthreads();

    // ---- GEMM2: A from ldsT image, B from ldsW ----
#pragma unroll
    for (int m = 0; m < 2; ++m)
#pragma unroll
        for (int n = 0; n < 8; ++n) acc[m][n] = zero;

#pragma unroll
    for (int kk = 0; kk < 4; ++kk) {
        int kbyte = kk * 64 + (lhi << 4);
        bf16x8 afrag[2];
#pragma unroll
        for (int m = 0; m < 2; ++m) {
            int rowl = m0 + m * 16 + l15;
            afrag[m] = *(const bf16x8*)((const char*)ldsT + rowl * 256 + (kbyte ^ ((rowl & 7) << 4)));
        }
#pragma unroll
        for (int n = 0; n < 8; ++n) {
            int col = n * 16 + l15;
            int addr = col * 256 + (kbyte ^ ((col & 7) << 4));
            bf16x8 bfrag = *(const bf16x8*)((const char*)ldsW + addr);
            acc[0][n] = __builtin_amdgcn_mfma_f32_16x16x32_bf16(afrag[0], bfrag, acc[0][n], 0, 0, 0);
            acc[1][n] = __builtin_amdgcn_mfma_f32_16x16x32_bf16(afrag[1], bfrag, acc[1][n], 0, 0, 0);
        }
    }

    // ---- z2 = acc + b2 (stays in registers); BN partial stats ----
    {
        float bc2[8];
#pragma unroll
        for (int n = 0; n < 8; ++n) bc2[n] = b2[n * 16 + l15];
#pragma unroll
        for (int m = 0; m < 2; ++m)
#pragma unroll
            for (int n = 0; n < 8; ++n)
#pragma unroll
                for (int r = 0; r < 4; ++r) acc[m][n][r] += bc2[n];
    }
    float s1[8], s2[8];
#pragma unroll
    for (int n = 0; n < 8; ++n) { s1[n] = 0.f; s2[n] = 0.f; }
#pragma unroll
    for (int m = 0; m < 2; ++m) {
        int rbase = brow + m0 + m * 16 + (lhi << 2);
#pragma unroll
        for (int r = 0; r < 4; ++r) {
            bool ok = (rbase + r) < NN;
            if (ok) {
#pragma unroll
                for (int n = 0; n < 8; ++n) {
                    float v = acc[m][n][r];
                    s1[n] += v;
                    s2[n] += v * v;
                }
            }
        }
    }
    __syncthreads();  // all LDS reads of GEMM2 done (ldsW, ldsT reusable)

    // stage hprev rows into ldsW (image layout, for the skip-add)
    {
        int row = tid >> 1, half = tid & 1;
        int grow = brow + row;
        if (grow >= NN) grow = NN - 1;
        const uint16_t* src = hprev + (size_t)grow * 128;
#pragma unroll
        for (int i = 0; i < 8; ++i) {
            int c = half * 8 + i;
            uint4 v = *(const uint4*)(src + c * 8);
            *(uint4*)((char*)ldsW + row * 256 + ((c * 16) ^ ((row & 7) << 4))) = v;
        }
    }
    // stats reduce in ldsT scratch
    float* ls = (float*)ldsT;
    ls[tid] = 0.f;
    __syncthreads();
#pragma unroll
    for (int n = 0; n < 8; ++n) {
        float a1 = s1[n] + __shfl_xor(s1[n], 16);
        a1 += __shfl_xor(a1, 32);
        float a2 = s2[n] + __shfl_xor(s2[n], 16);
        a2 += __shfl_xor(a2, 32);
        if (lane < 16) {
            atomicAdd(&ls[n * 16 + lane], a1);
            atomicAdd(&ls[128 + n * 16 + lane], a2);
        }
    }
    __syncthreads();
    atomicAdd(&bnsum[tid], ls[tid]);
    __syncthreads();  // drains the block's global atomics before the release-add

    // ---- device-scope grid barrier ----
    if (tid == 0) {
        __hip_atomic_fetch_add(barcnt, 1, __ATOMIC_RELEASE, __HIP_MEMORY_SCOPE_AGENT);
        while (__hip_atomic_load(barcnt, __ATOMIC_ACQUIRE, __HIP_MEMORY_SCOPE_AGENT) < target) {
            __builtin_amdgcn_s_sleep(2);
        }
    }
    __syncthreads();

    // BN coefficients (coherent reads)
    if (tid < 128) {
        float su = __hip_atomic_load(&bnsum[tid], __ATOMIC_RELAXED, __HIP_MEMORY_SCOPE_AGENT);
        float sq = __hip_atomic_load(&bnsum[128 + tid], __ATOMIC_RELAXED, __HIP_MEMORY_SCOPE_AGENT);
        float mu = su * (1.0f / NN);
        float var = sq * (1.0f / NN) - mu * mu;
        float a = gammal[tid] * rsqrtf(var + 1e-5f);
        sAB[tid] = a;
        sAB[128 + tid] = betal[tid] - mu * a;
    }
    __syncthreads();

    // ---- apply BN + skip + relu; write hnext image into ldsT ----
#pragma unroll
    for (int m = 0; m < 2; ++m) {
        int rbase = m0 + m * 16 + (lhi << 2);
#pragma unroll
        for (int r = 0; r < 4; ++r) {
            int row = rbase + r;
            int swz = (row & 7) << 4;
#pragma unroll
            for (int n = 0; n < 8; ++n) {
                int col = n * 16 + l15;
                float v = fmaf(sAB[col], acc[m][n][r], sAB[128 + col]);
                if (has_skip) {
                    uint16_t hv = *(const uint16_t*)((const char*)ldsW + row * 256 + ((col * 2) ^ swz));
                    v += bf1(hv);
                }
                v = fmaxf(v, 0.f);
                *(uint16_t*)((char*)ldsT + row * 256 + ((col * 2) ^ swz)) = f2bf(v);
            }
        }
    }
    __syncthreads();  // apply done: ldsW (hprev) dead, ldsT image complete

    // write hnext to global (vectorized from image); stage Wl into ldsW
    {
        int row = tid >> 1, half = tid & 1;
        int grow = brow + row;
        if (grow < NN) {
            uint16_t* dst = hnext + (size_t)grow * 128;
#pragma unroll
            for (int i = 0; i < 8; ++i) {
                int c = half * 8 + i;
                uint4 v = *(const uint4*)((const char*)ldsT + row * 256 + ((c * 16) ^ ((row & 7) << 4)));
                *(uint4*)(dst + c * 8) = v;
            }
        }
    }
#pragma unroll
    for (int it = 0; it < 8; ++it) *(bf16x8*)(&ldsW[(it * 256 + tid) * 8]) = wpre[it];
    __syncthreads();

    // ---- GEMM3: A = hnext image (ldsT), B = Wl (ldsW) ----
#pragma unroll
    for (int m = 0; m < 2; ++m)
#pragma unroll
        for (int n = 0; n < 8; ++n) acc[m][n] = zero;

#pragma unroll
    for (int kk = 0; kk < 4; ++kk) {
        int kbyte = kk * 64 + (lhi << 4);
        bf16x8 afrag[2];
#pragma unroll
        for (int m = 0; m < 2; ++m) {
            int rowl = m0 + m * 16 + l15;
            afrag[m] = *(const bf16x8*)((const char*)ldsT + rowl * 256 + (kbyte ^ ((rowl & 7) << 4)));
        }
#pragma unroll
        for (int n = 0; n < 8; ++n) {
            int col = n * 16 + l15;
            int addr = col * 256 + (kbyte ^ ((col & 7) << 4));
            bf16x8 bfrag = *(const bf16x8*)((const char*)ldsW + addr);
            acc[0][n] = __builtin_amdgcn_mfma_f32_16x16x32_bf16(afrag[0], bfrag, acc[0][n], 0, 0, 0);
            acc[1][n] = __builtin_amdgcn_mfma_f32_16x16x32_bf16(afrag[1], bfrag, acc[1][n], 0, 0, 0);
        }
    }

    float bc3[8];
#pragma unroll
    for (int n = 0; n < 8; ++n) bc3[n] = blv[n * 16 + l15];
#pragma unroll
    for (int m = 0; m < 2; ++m) {
        int rbase = brow + m0 + m * 16 + (lhi << 2);
#pragma unroll
        for (int r = 0; r < 4; ++r) {
            int row = rbase + r;
            if (row < NN) {
#pragma unroll
                for (int n = 0; n < 8; ++n) {
                    outl[(size_t)row * (NL * DD) + n * 16 + l15] = acc[m][n][r] + bc3[n];
                }
            }
        }
    }
}

extern "C" void kernel_launch(void* const* d_in, const int* in_sizes, int n_in,
                              void* d_out, int out_size, void* d_ws, size_t ws_size,
                              hipStream_t stream) {
    const float* x = (const float*)d_in[0];
    const int* ei = (const int*)d_in[1];
    const float* W1 = (const float*)d_in[2];
    const float* b1 = (const float*)d_in[3];
    const float* W2 = (const float*)d_in[4];
    const float* b2 = (const float*)d_in[5];
    const float* epsp = (const float*)d_in[6];
    const float* gamma = (const float*)d_in[7];
    const float* beta = (const float*)d_in[8];
    const float* Wl = (const float*)d_in[9];
    const float* bl = (const float*)d_in[10];
    float* out = (float*)d_out;

    char* w = (char*)d_ws;
    size_t off = 0;
    auto take = [&](size_t b) -> char* {
        char* p = w + off;
        off += (b + 255) & ~(size_t)255;
        return p;
    };
    uint16_t* hb[4];
    for (int i = 0; i < 4; ++i) hb[i] = (uint16_t*)take((size_t)NN * DD * 2);
    uint16_t* zb = (uint16_t*)take((size_t)NN * DD * 2);
    int* rowptr = (int*)take((size_t)(NN + 1) * 4);
    int* cursor = (int*)take((size_t)NN * 4);
    int* colv = (int*)take((size_t)NE * 4);
    int* bsum = (int*)take(128 * 4);
    int* bsoff = (int*)take(128 * 4);
    uint16_t* Wb = (uint16_t*)take(9 * 16384 * 2);
    float* bnsum = (float*)take(256 * 4);
    int* barcnt = (int*)take(256);

    const int* srcv = ei;        // edge_index[0]
    const int* dstv = ei + NE;   // edge_index[1]

    // weights + input conversion (x2bf also zeroes CSR cursor + barrier counter)
    k_convert_w<<<(9 * 16384 + 255) / 256, 256, 0, stream>>>(W1, W2, Wl, Wb);
    k_x2bf<<<(NN * DD / 4 + 255) / 256, 256, 0, stream>>>(x, hb[0], cursor, barcnt);

    // CSR build
    k_hist<<<(NE + 255) / 256, 256, 0, stream>>>(dstv, cursor);
    k_bsum<<<98, 512, 0, stream>>>(cursor, bsum);
    k_scanbs<<<1, 128, 0, stream>>>(bsum, bsoff);
    k_scan2<<<98, 512, 0, stream>>>(cursor, bsoff, rowptr);
    k_fill<<<(NE + 255) / 256, 256, 0, stream>>>(srcv, dstv, cursor, colv);

    const int agg_blocks = (NN * 16 + 255) / 256;  // 3125

    for (int l = 0; l < NL; ++l) {
        k_agg<<<agg_blocks, 256, 0, stream>>>(hb[l], rowptr, colv, epsp, l, zb, bnsum);
        k_layer<<<GB, 256, 0, stream>>>(zb, hb[l],
                                        Wb + l * 16384, Wb + (3 + l) * 16384, Wb + (6 + l) * 16384,
                                        b1 + l * 128, b2 + l * 128, bl + l * 128,
                                        gamma + l * 128, beta + l * 128,
                                        l > 0 ? 1 : 0, bnsum, barcnt, (l + 1) * GB,
                                        hb[l + 1], out + l * 128);
    }
}

// Round 7
// 263.310 us; speedup vs baseline: 1.1786x; 1.1786x over previous
//
#include <hip/hip_runtime.h>
#include <hip/hip_bf16.h>
#include <stdint.h>

#define NN 50000
#define NE 625000
#define DD 128
#define NL 3
#define GB 391  // gemm blocks = ceil(NN/128)

typedef __bf16 bf16x8 __attribute__((ext_vector_type(8)));
typedef float f32x4 __attribute__((ext_vector_type(4)));

__device__ __forceinline__ float bflo(uint32_t u) { return __uint_as_float(u << 16); }
__device__ __forceinline__ float bfhi(uint32_t u) { return __uint_as_float(u & 0xffff0000u); }
__device__ __forceinline__ uint16_t f2bf(float f) {
    __hip_bfloat16 h = __float2bfloat16(f);
    return __builtin_bit_cast(uint16_t, h);
}
__device__ __forceinline__ uint32_t pack2(float lo, float hi) {
    return (uint32_t)f2bf(lo) | ((uint32_t)f2bf(hi) << 16);
}

// ---------------- CSR construction ----------------
__global__ void k_hist(const int* __restrict__ dstv, int* __restrict__ deg) {
    int e = blockIdx.x * 256 + threadIdx.x;
    if (e < NE) atomicAdd(&deg[dstv[e]], 1);
}

__global__ __launch_bounds__(512) void k_bsum(const int* __restrict__ deg, int* __restrict__ bsum) {
    __shared__ int s[512];
    int i = blockIdx.x * 512 + threadIdx.x;
    int v = (i < NN) ? deg[i] : 0;
    s[threadIdx.x] = v;
    __syncthreads();
    for (int st = 256; st > 0; st >>= 1) {
        if (threadIdx.x < st) s[threadIdx.x] += s[threadIdx.x + st];
        __syncthreads();
    }
    if (threadIdx.x == 0) bsum[blockIdx.x] = s[0];
}

__global__ __launch_bounds__(128) void k_scanbs(const int* __restrict__ bsum, int* __restrict__ bsoff) {
    __shared__ int s[128];
    int t = threadIdx.x;
    int v = (t < 98) ? bsum[t] : 0;
    s[t] = v;
    __syncthreads();
    for (int st = 1; st < 128; st <<= 1) {
        int a = (t >= st) ? s[t - st] : 0;
        __syncthreads();
        s[t] += a;
        __syncthreads();
    }
    if (t < 98) bsoff[t] = s[t] - v;
}

__global__ __launch_bounds__(512) void k_scan2(int* __restrict__ deg_cursor,
                                               const int* __restrict__ bsoff,
                                               int* __restrict__ rowptr) {
    __shared__ int s[512];
    int t = threadIdx.x;
    int i = blockIdx.x * 512 + t;
    int v = (i < NN) ? deg_cursor[i] : 0;
    s[t] = v;
    __syncthreads();
    for (int st = 1; st < 512; st <<= 1) {
        int a = (t >= st) ? s[t - st] : 0;
        __syncthreads();
        s[t] += a;
        __syncthreads();
    }
    if (i < NN) {
        int excl = bsoff[blockIdx.x] + s[t] - v;
        rowptr[i] = excl;
        deg_cursor[i] = excl;  // becomes fill cursor
        if (i == NN - 1) rowptr[NN] = excl + v;
    }
}

__global__ void k_fill(const int* __restrict__ srcv, const int* __restrict__ dstv,
                       int* __restrict__ cursor, int* __restrict__ colv) {
    int e = blockIdx.x * 256 + threadIdx.x;
    if (e < NE) {
        int d = dstv[e];
        int p = atomicAdd(&cursor[d], 1);
        colv[p] = srcv[e];
    }
}

// ---------------- merged prep: weight convert + x->bf16 + cursor zero ----------------
// blocks [0,576): convert 9 weight matrices to bf16 transposed+swizzled images
// blocks [576,...): x -> bf16 h0, zero CSR cursor
#define WCONV_BLOCKS 576  // 9*16384/256
__global__ void k_prep(const float* __restrict__ x, uint16_t* __restrict__ hb,
                       int* __restrict__ cursor,
                       const float* __restrict__ W1, const float* __restrict__ W2,
                       const float* __restrict__ Wl, uint16_t* __restrict__ Wb) {
    int b = blockIdx.x;
    if (b < WCONV_BLOCKS) {
        int id = b * 256 + threadIdx.x;
        int m = id >> 14;
        int r = id & 16383;
        int k = r >> 7;
        int col = r & 127;
        const float* src;
        if (m < 3) src = W1 + m * 16384;
        else if (m < 6) src = W2 + (m - 3) * 16384;
        else src = Wl + (m - 6) * 16384;
        float v = src[k * 128 + col];
        // image layout: [col][k] with k-index XOR-swizzled by (col&7)<<3 (bf16 units)
        Wb[m * 16384 + col * 128 + (k ^ ((col & 7) << 3))] = f2bf(v);
        return;
    }
    int id = (b - WCONV_BLOCKS) * 256 + threadIdx.x;
    if (id < NN) cursor[id] = 0;
    int base = id * 4;
    if (base >= NN * DD) return;
    float4 v = *(const float4*)(x + base);
    uint2 st;
    st.x = pack2(v.x, v.y);
    st.y = pack2(v.z, v.w);
    *(uint2*)(hb + base) = st;
}

// ---------------- aggregation: z = (1+eps)*h + sum_{src in N(dst)} h[src] ----------------
// 16 lanes per node, 4 nodes per wave, edge loop unrolled x4.
// Block 0 also zeroes bnsum for this layer's stats (stream-order safe).
__global__ __launch_bounds__(256) void k_agg(const uint16_t* __restrict__ hb,
                                             const int* __restrict__ rowptr,
                                             const int* __restrict__ colv,
                                             const float* __restrict__ epsp, int layer,
                                             uint16_t* __restrict__ zb,
                                             float* __restrict__ bnsum) {
    if (blockIdx.x == 0) bnsum[threadIdx.x] = 0.f;  // 256 threads cover 256 floats
    int g = (blockIdx.x * 256 + threadIdx.x) >> 4;  // node id
    int l16 = threadIdx.x & 15;
    if (g >= NN) return;
    float onepe = 1.0f + epsp[layer];
    int beg = rowptr[g], end = rowptr[g + 1];
    const uint4* hp = (const uint4*)hb;  // row = 16 uint4
    float a0 = 0.f, a1 = 0.f, a2 = 0.f, a3 = 0.f, a4 = 0.f, a5 = 0.f, a6 = 0.f, a7 = 0.f;
    int j = beg;
    for (; j + 3 < end; j += 4) {
        int s0 = colv[j];
        int s1 = colv[j + 1];
        int s2 = colv[j + 2];
        int s3 = colv[j + 3];
        uint4 u0 = hp[(size_t)s0 * 16 + l16];
        uint4 u1 = hp[(size_t)s1 * 16 + l16];
        uint4 u2 = hp[(size_t)s2 * 16 + l16];
        uint4 u3 = hp[(size_t)s3 * 16 + l16];
        a0 += bflo(u0.x); a1 += bfhi(u0.x); a2 += bflo(u0.y); a3 += bfhi(u0.y);
        a4 += bflo(u0.z); a5 += bfhi(u0.z); a6 += bflo(u0.w); a7 += bfhi(u0.w);
        a0 += bflo(u1.x); a1 += bfhi(u1.x); a2 += bflo(u1.y); a3 += bfhi(u1.y);
        a4 += bflo(u1.z); a5 += bfhi(u1.z); a6 += bflo(u1.w); a7 += bfhi(u1.w);
        a0 += bflo(u2.x); a1 += bfhi(u2.x); a2 += bflo(u2.y); a3 += bfhi(u2.y);
        a4 += bflo(u2.z); a5 += bfhi(u2.z); a6 += bflo(u2.w); a7 += bfhi(u2.w);
        a0 += bflo(u3.x); a1 += bfhi(u3.x); a2 += bflo(u3.y); a3 += bfhi(u3.y);
        a4 += bflo(u3.z); a5 += bfhi(u3.z); a6 += bflo(u3.w); a7 += bfhi(u3.w);
    }
    for (; j < end; ++j) {
        int s0 = colv[j];
        uint4 u = hp[(size_t)s0 * 16 + l16];
        a0 += bflo(u.x); a1 += bfhi(u.x); a2 += bflo(u.y); a3 += bfhi(u.y);
        a4 += bflo(u.z); a5 += bfhi(u.z); a6 += bflo(u.w); a7 += bfhi(u.w);
    }
    uint4 hu = hp[(size_t)g * 16 + l16];
    a0 = fmaf(onepe, bflo(hu.x), a0); a1 = fmaf(onepe, bfhi(hu.x), a1);
    a2 = fmaf(onepe, bflo(hu.y), a2); a3 = fmaf(onepe, bfhi(hu.y), a3);
    a4 = fmaf(onepe, bflo(hu.z), a4); a5 = fmaf(onepe, bfhi(hu.z), a5);
    a6 = fmaf(onepe, bflo(hu.w), a6); a7 = fmaf(onepe, bfhi(hu.w), a7);
    uint4 st;
    st.x = pack2(a0, a1); st.y = pack2(a2, a3);
    st.z = pack2(a4, a5); st.w = pack2(a6, a7);
    ((uint4*)zb)[(size_t)g * 16 + l16] = st;
}

// ---------------- fused MLP: z2 = relu(zb @ W1 + b1) @ W2 + b2, + BN stats ----------------
// z2 stored as bf16 (stats computed from exact f32 acc before rounding).
__global__ __launch_bounds__(256) void k_mlp(const uint16_t* __restrict__ A,
                                             const uint16_t* __restrict__ W1img,
                                             const uint16_t* __restrict__ W2img,
                                             const float* __restrict__ b1,
                                             const float* __restrict__ b2,
                                             float* __restrict__ bnsum,
                                             uint16_t* __restrict__ z2b) {
    __shared__ uint16_t ldsW[16384];  // 32KB
    __shared__ uint16_t ldsT[16384];  // 32KB
    int tid = threadIdx.x;
    int wid = tid >> 6, lane = tid & 63;

    // prefetch W2 image into registers (ds_write after GEMM1 barrier)
    bf16x8 w2r[8];
#pragma unroll
    for (int it = 0; it < 8; ++it) w2r[it] = *(const bf16x8*)(W2img + (it * 256 + tid) * 8);

    // stage W1 image
#pragma unroll
    for (int it = 0; it < 8; ++it) {
        int idx = (it * 256 + tid) * 8;
        *(bf16x8*)(&ldsW[idx]) = *(const bf16x8*)(W1img + idx);
    }
    __syncthreads();

    const int brow = blockIdx.x * 128;
    const int m0 = wid * 32;
    const int l15 = lane & 15;
    const int lhi = lane >> 4;

    f32x4 acc[2][8];
    f32x4 zero = {0.f, 0.f, 0.f, 0.f};
#pragma unroll
    for (int m = 0; m < 2; ++m)
#pragma unroll
        for (int n = 0; n < 8; ++n) acc[m][n] = zero;

    // ---- GEMM1: A from global ----
    const char* Ab = (const char*)A;
#pragma unroll
    for (int kk = 0; kk < 4; ++kk) {
        int kbyte = kk * 64 + (lhi << 4);
        bf16x8 afrag[2];
#pragma unroll
        for (int m = 0; m < 2; ++m) {
            int row = brow + m0 + m * 16 + l15;
            if (row >= NN) row = NN - 1;
            afrag[m] = *(const bf16x8*)(Ab + (size_t)row * 256 + kbyte);
        }
#pragma unroll
        for (int n = 0; n < 8; ++n) {
            int col = n * 16 + l15;
            int addr = col * 256 + (kbyte ^ ((col & 7) << 4));
            bf16x8 bfrag = *(const bf16x8*)((const char*)ldsW + addr);
            acc[0][n] = __builtin_amdgcn_mfma_f32_16x16x32_bf16(afrag[0], bfrag, acc[0][n], 0, 0, 0);
            acc[1][n] = __builtin_amdgcn_mfma_f32_16x16x32_bf16(afrag[1], bfrag, acc[1][n], 0, 0, 0);
        }
    }

    // ---- epilogue1: relu(acc + b1) -> ldsT (bf16, W-image layout) ----
    {
        float bc[8];
#pragma unroll
        for (int n = 0; n < 8; ++n) bc[n] = b1[n * 16 + l15];
#pragma unroll
        for (int m = 0; m < 2; ++m) {
            int rbase = m0 + m * 16 + (lhi << 2);  // local row
#pragma unroll
            for (int r = 0; r < 4; ++r) {
                int row = rbase + r;
#pragma unroll
                for (int n = 0; n < 8; ++n) {
                    float v = fmaxf(acc[m][n][r] + bc[n], 0.f);
                    int col = n * 16 + l15;
                    int byteoff = row * 256 + ((col * 2) ^ ((row & 7) << 4));
                    *(uint16_t*)((char*)ldsT + byteoff) = f2bf(v);
                }
            }
        }
    }
    __syncthreads();  // GEMM1 W1-reads done + t1 writes done

    // stage W2 from regs
#pragma unroll
    for (int it = 0; it < 8; ++it) *(bf16x8*)(&ldsW[(it * 256 + tid) * 8]) = w2r[it];
    __syncthreads();

    // ---- GEMM2: A from ldsT, B from ldsW ----
#pragma unroll
    for (int m = 0; m < 2; ++m)
#pragma unroll
        for (int n = 0; n < 8; ++n) acc[m][n] = zero;

#pragma unroll
    for (int kk = 0; kk < 4; ++kk) {
        int kbyte = kk * 64 + (lhi << 4);
        bf16x8 afrag[2];
#pragma unroll
        for (int m = 0; m < 2; ++m) {
            int rowl = m0 + m * 16 + l15;
            afrag[m] = *(const bf16x8*)((const char*)ldsT + rowl * 256 + (kbyte ^ ((rowl & 7) << 4)));
        }
#pragma unroll
        for (int n = 0; n < 8; ++n) {
            int col = n * 16 + l15;
            int addr = col * 256 + (kbyte ^ ((col & 7) << 4));
            bf16x8 bfrag = *(const bf16x8*)((const char*)ldsW + addr);
            acc[0][n] = __builtin_amdgcn_mfma_f32_16x16x32_bf16(afrag[0], bfrag, acc[0][n], 0, 0, 0);
            acc[1][n] = __builtin_amdgcn_mfma_f32_16x16x32_bf16(afrag[1], bfrag, acc[1][n], 0, 0, 0);
        }
    }

    // ---- epilogue2: z2 (bf16) + BN stats from exact f32 ----
    float bc2[8];
#pragma unroll
    for (int n = 0; n < 8; ++n) bc2[n] = b2[n * 16 + l15];

    float s1[8], s2[8];
#pragma unroll
    for (int n = 0; n < 8; ++n) { s1[n] = 0.f; s2[n] = 0.f; }

#pragma unroll
    for (int m = 0; m < 2; ++m) {
        int rbase = brow + m0 + m * 16 + (lhi << 2);
#pragma unroll
        for (int r = 0; r < 4; ++r) {
            int row = rbase + r;
            bool ok = row < NN;
#pragma unroll
            for (int n = 0; n < 8; ++n) {
                float v = acc[m][n][r] + bc2[n];
                if (ok) {
                    z2b[(size_t)row * 128 + n * 16 + l15] = f2bf(v);
                    s1[n] += v;
                    s2[n] += v * v;
                }
            }
        }
    }

    __syncthreads();  // ldsT A-reads done; reuse for stats
    float* ls = (float*)ldsT;
    ls[tid] = 0.f;
    __syncthreads();
#pragma unroll
    for (int n = 0; n < 8; ++n) {
        float a1 = s1[n] + __shfl_xor(s1[n], 16);
        a1 += __shfl_xor(a1, 32);
        float a2 = s2[n] + __shfl_xor(s2[n], 16);
        a2 += __shfl_xor(a2, 32);
        if (lane < 16) {
            atomicAdd(&ls[n * 16 + lane], a1);
            atomicAdd(&ls[128 + n * 16 + lane], a2);
        }
    }
    __syncthreads();
    atomicAdd(&bnsum[tid], ls[tid]);
}

// ---------------- BN finalize (per-block) + apply + skip + relu -> next h (bf16) ----------------
__global__ __launch_bounds__(256) void k_apply(const uint16_t* __restrict__ z2b,
                                               const uint16_t* __restrict__ hin,
                                               const float* __restrict__ bnsum,
                                               const float* __restrict__ gamma,
                                               const float* __restrict__ beta, int layer,
                                               uint16_t* __restrict__ hout) {
    __shared__ float sA[128], sB[128];
    int tid = threadIdx.x;
    if (tid < 128) {
        float mu = bnsum[tid] * (1.0f / NN);
        float var = bnsum[128 + tid] * (1.0f / NN) - mu * mu;
        float a = gamma[layer * 128 + tid] * rsqrtf(var + 1e-5f);
        sA[tid] = a;
        sB[tid] = beta[layer * 128 + tid] - mu * a;
    }
    __syncthreads();
    int id = blockIdx.x * 256 + tid;
    int base = id * 4;
    if (base >= NN * DD) return;
    int c = base & 127;
    uint2 zu = *(const uint2*)(z2b + base);
    float4 av = *(const float4*)(sA + c);
    float4 bv = *(const float4*)(sB + c);
    float v0 = fmaf(av.x, bflo(zu.x), bv.x);
    float v1 = fmaf(av.y, bfhi(zu.x), bv.y);
    float v2 = fmaf(av.z, bflo(zu.y), bv.z);
    float v3 = fmaf(av.w, bfhi(zu.y), bv.w);
    if (layer > 0) {
        uint2 h = *(const uint2*)(hin + base);
        v0 += bflo(h.x);
        v1 += bfhi(h.x);
        v2 += bflo(h.y);
        v3 += bfhi(h.y);
    }
    v0 = fmaxf(v0, 0.f);
    v1 = fmaxf(v1, 0.f);
    v2 = fmaxf(v2, 0.f);
    v3 = fmaxf(v3, 0.f);
    uint2 st;
    st.x = pack2(v0, v1);
    st.y = pack2(v2, v3);
    *(uint2*)(hout + base) = st;
}

// ---------------- batched output GEMMs: out[:, l*128:(l+1)*128] = h(l+1) @ Wl[l] + bl[l] ----------------
__global__ __launch_bounds__(256) void k_outgemm(const uint16_t* __restrict__ h1,
                                                 const uint16_t* __restrict__ h2,
                                                 const uint16_t* __restrict__ h3,
                                                 const uint16_t* __restrict__ Wb6,
                                                 const float* __restrict__ bl,
                                                 float* __restrict__ out) {
    __shared__ uint16_t lds[16384];
    int layer = blockIdx.x / GB;
    int blk = blockIdx.x - layer * GB;
    const uint16_t* A = (layer == 0) ? h1 : ((layer == 1) ? h2 : h3);
    const uint16_t* Wimg = Wb6 + layer * 16384;
    const float* bias = bl + layer * 128;

    int tid = threadIdx.x;
    int wid = tid >> 6, lane = tid & 63;
#pragma unroll
    for (int it = 0; it < 8; ++it) {
        int idx = (it * 256 + tid) * 8;
        bf16x8 v = *(const bf16x8*)(Wimg + idx);
        *(bf16x8*)(&lds[idx]) = v;
    }
    __syncthreads();

    const int brow = blk * 128;
    const int m0 = wid * 32;
    const int l15 = lane & 15;
    const int lhi = lane >> 4;

    f32x4 acc[2][8];
    f32x4 zero = {0.f, 0.f, 0.f, 0.f};
#pragma unroll
    for (int m = 0; m < 2; ++m)
#pragma unroll
        for (int n = 0; n < 8; ++n) acc[m][n] = zero;

    const char* Ab = (const char*)A;
#pragma unroll
    for (int kk = 0; kk < 4; ++kk) {
        int kbyte = kk * 64 + (lhi << 4);
        bf16x8 afrag[2];
#pragma unroll
        for (int m = 0; m < 2; ++m) {
            int row = brow + m0 + m * 16 + l15;
            if (row >= NN) row = NN - 1;
            afrag[m] = *(const bf16x8*)(Ab + (size_t)row * 256 + kbyte);
        }
#pragma unroll
        for (int n = 0; n < 8; ++n) {
            int col = n * 16 + l15;
            int addr = col * 256 + (kbyte ^ ((col & 7) << 4));
            bf16x8 bfrag = *(const bf16x8*)((const char*)lds + addr);
            acc[0][n] = __builtin_amdgcn_mfma_f32_16x16x32_bf16(afrag[0], bfrag, acc[0][n], 0, 0, 0);
            acc[1][n] = __builtin_amdgcn_mfma_f32_16x16x32_bf16(afrag[1], bfrag, acc[1][n], 0, 0, 0);
        }
    }

    float bcol[8];
#pragma unroll
    for (int n = 0; n < 8; ++n) bcol[n] = bias[n * 16 + l15];

#pragma unroll
    for (int m = 0; m < 2; ++m) {
        int rbase = brow + m0 + m * 16 + (lhi << 2);
#pragma unroll
        for (int r = 0; r < 4; ++r) {
            int row = rbase + r;
            if (row < NN) {
#pragma unroll
                for (int n = 0; n < 8; ++n) {
                    float v = acc[m][n][r] + bcol[n];
                    out[(size_t)row * (NL * DD) + layer * 128 + n * 16 + l15] = v;
                }
            }
        }
    }
}

extern "C" void kernel_launch(void* const* d_in, const int* in_sizes, int n_in,
                              void* d_out, int out_size, void* d_ws, size_t ws_size,
                              hipStream_t stream) {
    const float* x = (const float*)d_in[0];
    const int* ei = (const int*)d_in[1];
    const float* W1 = (const float*)d_in[2];
    const float* b1 = (const float*)d_in[3];
    const float* W2 = (const float*)d_in[4];
    const float* b2 = (const float*)d_in[5];
    const float* epsp = (const float*)d_in[6];
    const float* gamma = (const float*)d_in[7];
    const float* beta = (const float*)d_in[8];
    const float* Wl = (const float*)d_in[9];
    const float* bl = (const float*)d_in[10];
    float* out = (float*)d_out;

    char* w = (char*)d_ws;
    size_t off = 0;
    auto take = [&](size_t b) -> char* {
        char* p = w + off;
        off += (b + 255) & ~(size_t)255;
        return p;
    };
    uint16_t* hb[4];
    for (int i = 0; i < 4; ++i) hb[i] = (uint16_t*)take((size_t)NN * DD * 2);
    uint16_t* zb = (uint16_t*)take((size_t)NN * DD * 2);
    uint16_t* z2b = (uint16_t*)take((size_t)NN * DD * 2);
    int* rowptr = (int*)take((size_t)(NN + 1) * 4);
    int* cursor = (int*)take((size_t)NN * 4);
    int* colv = (int*)take((size_t)NE * 4);
    int* bsum = (int*)take(128 * 4);
    int* bsoff = (int*)take(128 * 4);
    uint16_t* Wb = (uint16_t*)take(9 * 16384 * 2);
    float* bnsum = (float*)take(256 * 4);

    const int* srcv = ei;        // edge_index[0]
    const int* dstv = ei + NE;   // edge_index[1]

    // merged prep: weight convert + x->bf16 + cursor zero
    const int x2bf_blocks = (NN * DD / 4 + 255) / 256;  // 6250
    k_prep<<<WCONV_BLOCKS + x2bf_blocks, 256, 0, stream>>>(x, hb[0], cursor, W1, W2, Wl, Wb);

    // CSR build
    k_hist<<<(NE + 255) / 256, 256, 0, stream>>>(dstv, cursor);
    k_bsum<<<98, 512, 0, stream>>>(cursor, bsum);
    k_scanbs<<<1, 128, 0, stream>>>(bsum, bsoff);
    k_scan2<<<98, 512, 0, stream>>>(cursor, bsoff, rowptr);
    k_fill<<<(NE + 255) / 256, 256, 0, stream>>>(srcv, dstv, cursor, colv);

    const int agg_blocks = (NN * 16 + 255) / 256;  // 3125

    for (int l = 0; l < NL; ++l) {
        k_agg<<<agg_blocks, 256, 0, stream>>>(hb[l], rowptr, colv, epsp, l, zb, bnsum);
        k_mlp<<<GB, 256, 0, stream>>>(zb, Wb + l * 16384, Wb + (3 + l) * 16384,
                                      b1 + l * 128, b2 + l * 128, bnsum, z2b);
        k_apply<<<x2bf_blocks, 256, 0, stream>>>(z2b, hb[l], bnsum, gamma, beta,
                                                 l, hb[l + 1]);
    }
    k_outgemm<<<NL * GB, 256, 0, stream>>>(hb[1], hb[2], hb[3], Wb + 6 * 16384, bl, out);
}